// Round 1
// baseline (1113.960 us; speedup 1.0000x reference)
//
#include <hip/hip_runtime.h>
#include <math.h>

#define NSEQ 32
#define NH   32
#define NKV  8
#define QPK  4      // query heads per kv head
#define HD   128
#define BS   16
#define MAXB 256
#define SCALE 0.08838834764831845f

// One workgroup per (seq, kv_head). 4 waves; each wave owns context blocks
// strided by 4 and computes all 4 query heads of the group (KV read once).
// Per-wave online softmax; 4-way merge through LDS at the end.
__launch_bounds__(256, 1)
__global__ void pa_decode(const float* __restrict__ q,
                          const float* __restrict__ kc,
                          const float* __restrict__ vc,
                          const int* __restrict__ bt,
                          const int* __restrict__ ctxlen,
                          float* __restrict__ out)
{
    const int bid  = blockIdx.x;
    const int seq  = bid >> 3;
    const int kvh  = bid & 7;
    const int tid  = threadIdx.x;
    const int wave = tid >> 6;
    const int lane = tid & 63;

    __shared__ float q_s[QPK * HD];
    __shared__ float m_s[4][QPK];
    __shared__ float l_s[4][QPK];
    __shared__ float acc_s[4][QPK][HD];

    // stage scaled q into LDS (heads of this kv group are contiguous)
    {
        const float* qp = q + ((long)seq * NH + kvh * QPK) * HD;
        for (int i = tid; i < QPK * HD; i += 256)
            q_s[i] = qp[i] * SCALE;
    }
    __syncthreads();

    const int clen = ctxlen[seq];
    const int nblk = (clen + BS - 1) >> 4;
    const int* btrow = bt + seq * MAXB;

    // phase-1 (QK) lane mapping: token pair {t_lo, t_lo+8}, dim group g8 -> dims [g8*16, g8*16+16)
    const int t_lo = lane & 7;
    const int g8   = lane >> 3;

    // q fragment in registers: 4 heads x 16 dims
    float4 qreg[QPK][4];
    #pragma unroll
    for (int h = 0; h < QPK; ++h)
        #pragma unroll
        for (int j = 0; j < 4; ++j)
            qreg[h][j] = *(const float4*)&q_s[h * HD + g8 * 16 + j * 4];

    float m[QPK], l[QPK], acc0[QPK], acc1[QPK];
    #pragma unroll
    for (int h = 0; h < QPK; ++h) {
        m[h] = -INFINITY; l[h] = 0.f; acc0[h] = 0.f; acc1[h] = 0.f;
    }

    for (int blk = wave; blk < nblk; blk += 4) {
        const long pb = btrow[blk];
        const float* kbase = kc + ((long)pb * NKV + kvh) * (HD / 8) * BS * 8;
        const float* vbase = vc + ((long)pb * NKV + kvh) * HD * BS;

        // ---- K loads: o in {2*g8, 2*g8+1}, t in {t_lo, t_lo+8}; layout o*128 + t*8 + inner
        float4 kf[2][2][2];
        #pragma unroll
        for (int oo = 0; oo < 2; ++oo)
            #pragma unroll
            for (int tt = 0; tt < 2; ++tt) {
                const float* p = kbase + (g8 * 2 + oo) * (BS * 8) + (t_lo + tt * 8) * 8;
                kf[oo][tt][0] = *(const float4*)p;
                kf[oo][tt][1] = *(const float4*)(p + 4);
            }

        // ---- V loads: dims {lane, lane+64}, 16 contiguous t each; layout d*16 + t
        float vv0[BS], vv1[BS];
        {
            const float* p0 = vbase + (long)lane * BS;
            const float* p1 = vbase + (long)(lane + 64) * BS;
            #pragma unroll
            for (int j = 0; j < 4; ++j) {
                *(float4*)&vv0[j * 4] = *(const float4*)(p0 + j * 4);
                *(float4*)&vv1[j * 4] = *(const float4*)(p1 + j * 4);
            }
        }

        // ---- QK dot (partial over this lane's 16 dims)
        float lg[QPK][2];
        #pragma unroll
        for (int h = 0; h < QPK; ++h)
            #pragma unroll
            for (int tt = 0; tt < 2; ++tt) {
                float s = 0.f;
                #pragma unroll
                for (int oo = 0; oo < 2; ++oo) {
                    float4 a0 = qreg[h][oo * 2], a1 = qreg[h][oo * 2 + 1];
                    float4 k0 = kf[oo][tt][0],  k1 = kf[oo][tt][1];
                    s = fmaf(a0.x, k0.x, s); s = fmaf(a0.y, k0.y, s);
                    s = fmaf(a0.z, k0.z, s); s = fmaf(a0.w, k0.w, s);
                    s = fmaf(a1.x, k1.x, s); s = fmaf(a1.y, k1.y, s);
                    s = fmaf(a1.z, k1.z, s); s = fmaf(a1.w, k1.w, s);
                }
                lg[h][tt] = s;
            }

        // reduce over dim groups (lanes differing in bits 3..5)
        #pragma unroll
        for (int h = 0; h < QPK; ++h)
            #pragma unroll
            for (int tt = 0; tt < 2; ++tt) {
                float s = lg[h][tt];
                s += __shfl_xor(s, 8);
                s += __shfl_xor(s, 16);
                s += __shfl_xor(s, 32);
                lg[h][tt] = s;
            }

        // mask invalid tokens
        const int tok0 = blk * BS + t_lo;
        #pragma unroll
        for (int h = 0; h < QPK; ++h) {
            if (tok0 >= clen)     lg[h][0] = -INFINITY;
            if (tok0 + 8 >= clen) lg[h][1] = -INFINITY;
        }

        // ---- online softmax update (values are uniform across g8 lanes)
        float alpha[QPK], pr[QPK][2];
        #pragma unroll
        for (int h = 0; h < QPK; ++h) {
            float bm = fmaxf(lg[h][0], lg[h][1]);
            bm = fmaxf(bm, __shfl_xor(bm, 1));
            bm = fmaxf(bm, __shfl_xor(bm, 2));
            bm = fmaxf(bm, __shfl_xor(bm, 4));
            const float m_new = fmaxf(m[h], bm);
            alpha[h] = __expf(m[h] - m_new);     // 0 when m was -inf
            m[h] = m_new;
            pr[h][0] = __expf(lg[h][0] - m_new); // 0 when masked
            pr[h][1] = __expf(lg[h][1] - m_new);
            float s = pr[h][0] + pr[h][1];
            s += __shfl_xor(s, 1);
            s += __shfl_xor(s, 2);
            s += __shfl_xor(s, 4);
            l[h] = l[h] * alpha[h] + s;
        }

        // ---- PV: lane owns dims {lane, lane+64}; broadcast p over the wave
        #pragma unroll
        for (int h = 0; h < QPK; ++h) {
            float s0 = 0.f, s1 = 0.f;
            #pragma unroll
            for (int t = 0; t < BS; ++t) {
                const float pt = __shfl(pr[h][t >> 3], t & 7);
                s0 = fmaf(pt, vv0[t], s0);
                s1 = fmaf(pt, vv1[t], s1);
            }
            acc0[h] = fmaf(acc0[h], alpha[h], s0);
            acc1[h] = fmaf(acc1[h], alpha[h], s1);
        }
    }

    // ---- merge 4 waves
    if (lane == 0) {
        #pragma unroll
        for (int h = 0; h < QPK; ++h) { m_s[wave][h] = m[h]; l_s[wave][h] = l[h]; }
    }
    #pragma unroll
    for (int h = 0; h < QPK; ++h) {
        acc_s[wave][h][lane]      = acc0[h];
        acc_s[wave][h][lane + 64] = acc1[h];
    }
    __syncthreads();

    for (int i = tid; i < QPK * HD; i += 256) {
        const int h = i >> 7;
        const int d = i & (HD - 1);
        float M = -INFINITY;
        #pragma unroll
        for (int w = 0; w < 4; ++w) M = fmaxf(M, m_s[w][h]);
        float den = 0.f, num = 0.f;
        #pragma unroll
        for (int w = 0; w < 4; ++w) {
            const float a = __expf(m_s[w][h] - M);   // 0 for idle waves (m=-inf)
            den = fmaf(l_s[w][h], a, den);
            num = fmaf(acc_s[w][h][d], a, num);
        }
        out[((long)seq * NH + kvh * QPK + h) * HD + d] = num / den;
    }
}

extern "C" void kernel_launch(void* const* d_in, const int* in_sizes, int n_in,
                              void* d_out, int out_size, void* d_ws, size_t ws_size,
                              hipStream_t stream) {
    const float* q  = (const float*)d_in[0];
    const float* kc = (const float*)d_in[1];
    const float* vc = (const float*)d_in[2];
    const int* bt   = (const int*)d_in[3];
    const int* cl   = (const int*)d_in[4];
    float* out      = (float*)d_out;

    pa_decode<<<dim3(NSEQ * NKV), dim3(256), 0, stream>>>(q, kc, vc, bt, cl, out);
}